// Round 7
// baseline (144.731 us; speedup 1.0000x reference)
//
#include <hip/hip_runtime.h>

#define CCH   256
#define FH    96
#define FW    96
#define HW    (FH*FW)
#define SCALE 0.0625f

#define G     14            // sample rows/cols (OUT_SIZE*SAMPLE_NUM)
#define VSTR  28            // V row stride (floats); cols 24..27 zeroed pad
#define PLANE (G*VSTR)      // 392 floats per wave plane
#define WCH   32            // channels per wave
#define NSLOT 84            // 14 gy-rows x 6 quads, static

// Separable RoIAlign: staging computes the y-interpolated surface
// V[gy][col] = wyl*F[ylo][col] + wyh*F[ylo+1][col]  (y-validity in wyl/wyh),
// so each output needs only 4 ds_read2_b32 (R6 was LDS-read bound at 8).
// Wave-autonomous, no main-loop barriers; all addresses clamped by
// construction (R4 lesson). (256,6): 85-VGPR cap, no spill (R2 lesson).
__global__ __launch_bounds__(256, 6)
void roialign_kernel(const float* __restrict__ feat,
                     const float* __restrict__ rois,
                     float* __restrict__ out)
{
    __shared__ __align__(16) float vbuf[4 * PLANE];
    __shared__ int   s_lo[2][G];
    __shared__ float s_wl[2][G], s_wh[2][G];

    const int k    = blockIdx.x >> 1;
    const int half = blockIdx.x & 1;
    const int tid  = threadIdx.x;
    const int w    = tid >> 6;
    const int ll   = tid & 63;

    // ---------- Phase A: per-roi sample coords ----------
    const float x1 = rois[k*5+1] * SCALE;
    const float y1 = rois[k*5+2] * SCALE;
    const float x2 = rois[k*5+3] * SCALE;
    const float y2 = rois[k*5+4] * SCALE;
    const int   b  = (int)rois[k*5+0];
    const float binw = fmaxf(x2 - x1, 1.0f) * (1.0f/7.0f);
    const float binh = fmaxf(y2 - y1, 1.0f) * (1.0f/7.0f);

    if (tid < 28) {
        const int   axis  = (tid >= 14) ? 1 : 0;
        const int   g     = axis ? tid - 14 : tid;
        const float start = axis ? x1 : y1;
        const float bsz   = axis ? binw : binh;
        const float offs  = (float)(g >> 1) + 0.25f + 0.5f*(float)(g & 1);
        const float coord = start + bsz * offs;
        const bool  valid = (coord >= -1.0f) && (coord <= 96.0f);
        const float cc    = fminf(fmaxf(coord, 0.0f), 95.0f);
        const float lof   = floorf(cc);
        const float frac  = cc - lof;
        const float v     = valid ? 1.0f : 0.0f;
        s_lo[axis][g] = (int)lof;
        s_wl[axis][g] = (1.0f - frac) * v;
        s_wh[axis][g] = frac * v;
    }
    __syncthreads();   // the ONLY barrier

    const int col0 = min(s_lo[1][0] & ~3, FW - 24);   // 24-col window in-image
    float* const wp = &vbuf[w * PLANE];

    // Zero the plane once: pad cols 24..27 stay zero forever (writes only touch
    // cols 0..23), covering the weight-0 read at clo+1==24 when xlo clamps.
    {
        const float4 z = make_float4(0.f, 0.f, 0.f, 0.f);
        if (ll      < PLANE/4) *(float4*)&wp[ll*4]       = z;
        if (ll + 64 < PLANE/4) *(float4*)&wp[(ll+64)*4]  = z;
    }

    // ---------- staging-slot constants (channel-invariant, static 84 slots) ----
    // slot A = ll (always valid, 64<84); slot B = ll+64 (valid for ll<20)
    const int  gyA = ll / 6,  qA = ll - 6*gyA;          // gyA <= 10
    const int  sB  = ll + 64;
    const bool LB  = sB < NSLOT;
    const int  gyB = min(sB / 6, G-1);
    const int  qB  = min(sB - 6*gyB, 5);                // clamped legal for all lanes
    const float wylA = s_wl[0][gyA], wyhA = s_wh[0][gyA];
    const float wylB = s_wl[0][gyB], wyhB = s_wh[0][gyB];
    const int  rloA = s_lo[0][gyA], rhiA = min(rloA + 1, FH-1);
    const int  rloB = s_lo[0][gyB], rhiB = min(rloB + 1, FH-1);
    const int  goffAL = rloA*FW + col0 + 4*qA;
    const int  goffAH = rhiA*FW + col0 + 4*qA;
    const int  goffBL = rloB*FW + col0 + 4*qB;
    const int  goffBH = rhiB*FW + col0 + 4*qB;
    const int  ldA = gyA*VSTR + 4*qA;
    const int  ldB = gyB*VSTR + 4*qB;

    // ---------- tap constants (channel-invariant) ----------
    const bool active = ll < 49;
    const int  p  = active ? ll : 0;
    const int  oy = p / 7;
    const int  ox = p - oy*7;
    const int  gxA = 2*ox, gxB = 2*ox + 1;
    const int  cloA = min(max(s_lo[1][gxA] - col0, 0), 23);
    const int  cloB = min(max(s_lo[1][gxB] - col0, 0), 23);
    const float wxlA = s_wl[1][gxA]*0.25f, wxhA = s_wh[1][gxA]*0.25f;
    const float wxlB = s_wl[1][gxB]*0.25f, wxhB = s_wh[1][gxB]*0.25f;
    // reads: tp[0], tp[1], tp[VSTR], tp[VSTR+1]  ->  2x ds_read2_b32 each
    const float* tpA = wp + (2*oy)*VSTR + cloA;         // max 12*28+23 -> +29 = 388 < 392
    const float* tpB = wp + (2*oy)*VSTR + cloB;

    const int    cb   = half*128 + w*WCH;
    const float* gch  = feat + (size_t)(b*CCH + cb) * HW;
    float*       outp = out  + ((size_t)k*CCH + cb)*49 + p;

    float4 aL, aH, bL, bH;
    aL = *(const float4*)(gch + goffAL);
    aH = *(const float4*)(gch + goffAH);
    if (LB) { bL = *(const float4*)(gch + goffBL);
              bH = *(const float4*)(gch + goffBH); }

    for (int c = 0; c < WCH; ++c) {
        // y-interp + write V (vmcnt wait for this channel's loads lands here;
        // within-wave ds ordering keeps prior iter's reads ahead of these writes)
        {
            float4 v;
            v.x = wylA*aL.x + wyhA*aH.x;  v.y = wylA*aL.y + wyhA*aH.y;
            v.z = wylA*aL.z + wyhA*aH.z;  v.w = wylA*aL.w + wyhA*aH.w;
            *(float4*)&wp[ldA] = v;
        }
        if (LB) {
            float4 v;
            v.x = wylB*bL.x + wyhB*bH.x;  v.y = wylB*bL.y + wyhB*bH.y;
            v.z = wylB*bL.z + wyhB*bH.z;  v.w = wylB*bL.w + wyhB*bH.w;
            *(float4*)&wp[ldB] = v;
        }

        if (c + 1 < WCH) {                   // next channel's rows in flight
            const float* gn = gch + (size_t)(c+1)*HW;
            aL = *(const float4*)(gn + goffAL);
            aH = *(const float4*)(gn + goffAH);
            if (LB) { bL = *(const float4*)(gn + goffBL);
                      bH = *(const float4*)(gn + goffBH); }
        }

        if (active) {
            // x-weights are sy-invariant -> fold the two sample rows by addition
            const float sA0 = tpA[0] + tpA[VSTR];
            const float sA1 = tpA[1] + tpA[VSTR+1];
            const float sB0 = tpB[0] + tpB[VSTR];
            const float sB1 = tpB[1] + tpB[VSTR+1];
            outp[0] = wxlA*sA0 + wxhA*sA1 + wxlB*sB0 + wxhB*sB1;
        }
        outp += 49;
    }
}

extern "C" void kernel_launch(void* const* d_in, const int* in_sizes, int n_in,
                              void* d_out, int out_size, void* d_ws, size_t ws_size,
                              hipStream_t stream) {
    const float* feat = (const float*)d_in[0];
    const float* rois = (const float*)d_in[1];
    float*       outp = (float*)d_out;
    const int K = in_sizes[1] / 5;   // 1024
    roialign_kernel<<<K*2, 256, 0, stream>>>(feat, rois, outp);
}